// Round 11
// baseline (5253.554 us; speedup 1.0000x reference)
//
#include <hip/hip_runtime.h>
#include <math.h>

typedef __attribute__((ext_vector_type(8))) short bf16x8;   // 8 bf16 (4 VGPR)
typedef __attribute__((ext_vector_type(4))) float f32x4;    // MFMA C/D

static constexpr int Tt = 1024;
static constexpr int Hh = 512;
static constexpr int Cc = 10;

static constexpr int NXCD = 8;       // XCDs; each runs an independent group
static constexpr int BPX  = 32;      // blocks (CUs) per XCD
static constexpr int UPB  = 16;      // hidden units per block (64 gate rows)
static constexpr int NB   = 16;      // batch rows per XCD (8*16 = 128)
static constexpr int THREADS = 512;  // 8 waves = (gate-pair x K-quarter)
static constexpr int GRID = 256;     // 1 block per CU (LDS-forced, 84 KB)

// ws bytes: [0,1024) flags[8][32] | [1024,2048) rank counters | pad
//           [4096, +256KB) h_hi[2][8][16][512] bf16 | then h_lo 256KB
static constexpr size_t WS_HHI_B = 4096;
static constexpr size_t WS_HLO_B = 4096 + 262144;

__device__ __forceinline__ unsigned short f2bf(float f) {
    unsigned u = __builtin_bit_cast(unsigned, f);
    return (unsigned short)((u + 0x7FFFu + ((u >> 16) & 1u)) >> 16);   // RNE
}
__device__ __forceinline__ float bf2f(unsigned short h) {
    unsigned u = ((unsigned)h) << 16;
    return __builtin_bit_cast(float, u);
}
__device__ __forceinline__ float dot4(float4 a, float4 b) {
    return a.x * b.x + a.y * b.y + a.z * b.z + a.w * b.w;
}
__device__ __forceinline__ float fsig(float x) {
    const float e = __builtin_amdgcn_exp2f(x * -1.44269504f);
    return __builtin_amdgcn_rcpf(1.0f + e);
}
__device__ __forceinline__ float ftanh(float x) {
    const float e = __builtin_amdgcn_exp2f(x * -2.88539008f);
    return 2.0f * __builtin_amdgcn_rcpf(1.0f + e) - 1.0f;
}

__global__ __launch_bounds__(THREADS, 2)
void lstm_fused(const float* __restrict__ x,
                const float* __restrict__ w_ih,
                const float* __restrict__ w_hh,
                const float* __restrict__ b_ih,
                const float* __restrict__ b_hh,
                const float* __restrict__ w_t,
                const float* __restrict__ w_fc,
                const float* __restrict__ b_fc,
                float* __restrict__ out,
                float* __restrict__ ws)
{
    const int tid   = threadIdx.x;
    const int lane  = tid & 63;
    const int wv    = tid >> 6;         // 0..7
    const int mpair = wv & 1;           // gate pair: {0,1} or {2,3}
    const int kq    = wv >> 1;          // K quarter: kk in [kq*4, kq*4+4)
    const int frow  = lane & 15;        // fragment row (A) / batch col (B)
    const int kgrp  = lane >> 4;        // 8-elem K group within 32-K step

    int* flags    = (int*)ws;                 // [xcd*32 + rank]
    int* counters = (int*)ws + 256;           // init-time rank claim
    unsigned short* hg_hi = (unsigned short*)((char*)ws + WS_HHI_B);
    unsigned short* hg_lo = (unsigned short*)((char*)ws + WS_HLO_B);

    // LDS: h double-buffered hi/lo (64 KB) + gbuf partials (20 KB) = 84 KB
    __shared__ __align__(16) short hhi_ls[2][16 * 512];
    __shared__ __align__(16) short hlo_ls[2][16 * 512];
    __shared__ __align__(16) float gbuf[4 * 64 * 20];   // [kq][gaterow][batch]
    int* xchg = (int*)gbuf;                   // init-time only

    // ---- discover physical XCD, claim a rank ----
    if (tid == 0) {
        int xr;
        asm volatile("s_getreg_b32 %0, hwreg(20, 0, 32)" : "=s"(xr));
        const int xcd = xr & 7;
        xchg[0] = xcd;
        xchg[1] = atomicAdd(&counters[xcd * 32], 1) & 31;
    }
    __syncthreads();
    const int xcd  = xchg[0];
    const int rank = xchg[1];
    __syncthreads();                          // reads done before gbuf reuse
    const int fbase = xcd * BPX;

    // ---- W fragments into registers: 2 gates x 4 kk x (hi,lo) = 64 VGPR ----
    bf16x8 wahi[2][4], walo[2][4];
    #pragma unroll
    for (int mt = 0; mt < 2; ++mt) {
        const int gate = mpair * 2 + mt;
        const float* wr = w_hh + (size_t)(gate * Hh + rank * UPB + frow) * Hh;
        #pragma unroll
        for (int kk = 0; kk < 4; ++kk) {
            const float4* s = (const float4*)(wr + (kq * 4 + kk) * 32 + kgrp * 8);
            const float4 f0 = s[0], f1 = s[1];
            const float f[8] = { f0.x, f0.y, f0.z, f0.w, f1.x, f1.y, f1.z, f1.w };
            bf16x8 vhi, vlo;
            #pragma unroll
            for (int j = 0; j < 8; ++j) {
                const unsigned short hb = f2bf(f[j]);
                vhi[j] = (short)hb;
                vlo[j] = (short)f2bf(f[j] - bf2f(hb));
            }
            wahi[mt][kk] = vhi;
            walo[mt][kk] = vlo;
        }
    }

    // ---- elementwise role (tid < 256): thread -> (u, b) ----
    const int u  = tid & 15;
    const int b_ = (tid >> 4) & 15;
    const int gj = rank * UPB + u;
    const int gb = xcd * NB + b_;
    float wih_r[4], bias_r[4];
    #pragma unroll
    for (int g = 0; g < 4; ++g) {
        wih_r[g]  = w_ih[g * Hh + gj];
        bias_r[g] = b_ih[g * Hh + gj] + b_hh[g * Hh + gj];
    }
    float creg = 0.0f;

    // ---- owner role: ranks 0..15 own batch row xcd*16+rank ----
    const bool owner = (rank < NB);
    const int  gb_own = xcd * NB + rank;
    float S1w[Cc], S2w[Cc], bfc_r[Cc];
    #pragma unroll
    for (int c = 0; c < Cc; ++c) { S1w[c] = 0.f; S2w[c] = 0.f; bfc_r[c] = b_fc[c]; }

    for (int t = 0; t <= Tt; ++t) {
        const int rb = t & 1, wb = rb ^ 1;
        char* Lhi = (char*)hhi_ls[rb];
        char* Llo = (char*)hlo_ls[rb];

        // ---- A1: stage h_t hi/lo (16 x 512 bf16 each) into swizzled LDS ----
        if (t == 0) {
            const bf16x8 z = { 0, 0, 0, 0, 0, 0, 0, 0 };
            #pragma unroll
            for (int it = 0; it < 2; ++it) {
                const int idx = it * 512 + tid;
                const int row = idx >> 6, kg = idx & 63;
                const int off = (row * 1024 + kg * 16) ^ ((row & 7) << 4);
                *(bf16x8*)(Lhi + off) = z;
                *(bf16x8*)(Llo + off) = z;
            }
        } else if (t < Tt) {
            const bf16x8* shi = (const bf16x8*)(hg_hi + (size_t)(rb * NXCD + xcd) * NB * Hh);
            const bf16x8* slo = (const bf16x8*)(hg_lo + (size_t)(rb * NXCD + xcd) * NB * Hh);
            #pragma unroll
            for (int it = 0; it < 2; ++it) {
                const int idx = it * 512 + tid;
                const int row = idx >> 6, kg = idx & 63;
                const bf16x8 vhi = shi[idx];
                const bf16x8 vlo = slo[idx];
                const int off = (row * 1024 + kg * 16) ^ ((row & 7) << 4);
                *(bf16x8*)(Lhi + off) = vhi;
                *(bf16x8*)(Llo + off) = vlo;
            }
        }

        // ---- A2: owner emits step t-1's outputs (reads same h buffer) ----
        if (t > 0 && wv == 0 && owner) {
            const size_t rbase = ((size_t)(rb * NXCD + xcd) * NB + rank) * Hh + lane * 8;
            const bf16x8 vh = *(const bf16x8*)(hg_hi + rbase);
            const bf16x8 vl = *(const bf16x8*)(hg_lo + rbase);
            float f[8];
            #pragma unroll
            for (int j = 0; j < 8; ++j)
                f[j] = bf2f((unsigned short)vh[j]) + bf2f((unsigned short)vl[j]);
            const float4 hA = make_float4(f[0], f[1], f[2], f[3]);
            const float4 hB = make_float4(f[4], f[5], f[6], f[7]);
            const float4* wt4 = (const float4*)w_t;
            const float4* wf4 = (const float4*)w_fc;
            float r[12];
            r[0] = dot4(hA, wt4[lane * 2])       + dot4(hB, wt4[lane * 2 + 1]);
            r[1] = dot4(hA, wt4[128 + lane * 2]) + dot4(hB, wt4[128 + lane * 2 + 1]);
            #pragma unroll
            for (int c = 0; c < Cc; ++c)
                r[2 + c] = dot4(hA, wf4[c * 128 + lane * 2])
                         + dot4(hB, wf4[c * 128 + lane * 2 + 1]);
            #pragma unroll
            for (int m = 1; m <= 32; m <<= 1)
                #pragma unroll
                for (int k2 = 0; k2 < 12; ++k2)
                    r[k2] += __shfl_xor(r[k2], m, 64);

            if (lane == 0) {
                const float a = r[0], b2 = r[1];
                float* po = out + ((size_t)gb_own * Tt + (t - 1)) * Cc;
                #pragma unroll
                for (int c = 0; c < Cc; ++c) {
                    const float hw = r[2 + c];
                    po[c] = hw + a * S1w[c] + S2w[c] + bfc_r[c];
                    S1w[c] += hw;
                    S2w[c] += b2 * hw;
                }
            }
        }
        if (t == Tt) break;

        float xv = 0.f;
        if (tid < 256) xv = x[(size_t)gb * Tt + t];
        __syncthreads();

        // ---- B: GEMM 64x16x512; W in regs, only B(h) from LDS; 3-pass ----
        f32x4 acc[2][3];
        #pragma unroll
        for (int mt = 0; mt < 2; ++mt)
            #pragma unroll
            for (int p = 0; p < 3; ++p)
                acc[mt][p] = f32x4{ 0.f, 0.f, 0.f, 0.f };

        #pragma unroll
        for (int kk = 0; kk < 4; ++kk) {
            const int kabs = kq * 4 + kk;
            const int bo = (frow * 1024 + kgrp * 16 + kabs * 64) ^ ((lane & 7) << 4);
            const bf16x8 bhi = *(const bf16x8*)(Lhi + bo);
            const bf16x8 blo = *(const bf16x8*)(Llo + bo);
            #pragma unroll
            for (int mt = 0; mt < 2; ++mt) {
                acc[mt][0] = __builtin_amdgcn_mfma_f32_16x16x32_bf16(wahi[mt][kk], bhi, acc[mt][0], 0, 0, 0);
                acc[mt][1] = __builtin_amdgcn_mfma_f32_16x16x32_bf16(wahi[mt][kk], blo, acc[mt][1], 0, 0, 0);
                acc[mt][2] = __builtin_amdgcn_mfma_f32_16x16x32_bf16(walo[mt][kk], bhi, acc[mt][2], 0, 0, 0);
            }
        }
        // partial C -> gbuf[kq]; C layout: col=lane&15, row=(lane>>4)*4+reg
        {
            const int u0 = kgrp * 4;
            #pragma unroll
            for (int mt = 0; mt < 2; ++mt) {
                const int g = mpair * 2 + mt;
                #pragma unroll
                for (int r = 0; r < 4; ++r)
                    gbuf[(kq * 64 + g * 16 + u0 + r) * 20 + frow] =
                        acc[mt][0][r] + acc[mt][1][r] + acc[mt][2][r];
            }
        }
        __syncthreads();

        // ---- C: sum K-quarter partials, LSTM elementwise, write h hi/lo ----
        if (tid < 256) {
            float gs[4];
            #pragma unroll
            for (int g = 0; g < 4; ++g) {
                const int base = (g * 16 + u) * 20 + b_;
                gs[g] = gbuf[base] + gbuf[base + 1280]
                      + gbuf[base + 2560] + gbuf[base + 3840];
            }
            const float gi = gs[0] + xv * wih_r[0] + bias_r[0];
            const float gf = gs[1] + xv * wih_r[1] + bias_r[1];
            const float gg = gs[2] + xv * wih_r[2] + bias_r[2];
            const float go = gs[3] + xv * wih_r[3] + bias_r[3];
            creg = fsig(gf) * creg + fsig(gi) * ftanh(gg);
            const float hnew = fsig(go) * ftanh(creg);
            const unsigned short hb2 = f2bf(hnew);
            const unsigned short lb2 = f2bf(hnew - bf2f(hb2));
            const size_t hoff = ((size_t)(wb * NXCD + xcd) * NB + b_) * Hh + gj;
            hg_hi[hoff] = hb2;
            hg_lo[hoff] = lb2;
        }
        __syncthreads();   // vmcnt(0) drained before flag: h visible in XCD L2

        // ---- D: plain-store flag (ordered after h by the drain above) ----
        if (tid == 0)
            *(volatile int*)(flags + fbase + rank) = t + 1;

        // ---- E: lanes 0-31 of wave 0 poll 32 flags via L2 (no atomics) ----
        if (tid < 32) {
            const volatile int* fl = (const volatile int*)(flags + fbase + tid);
            int v = *fl;
            while (__any(v < t + 1)) {
                __builtin_amdgcn_s_sleep(1);
                asm volatile("buffer_inv\n\ts_waitcnt vmcnt(0)" ::: "memory");
                v = *fl;
            }
            asm volatile("buffer_inv\n\ts_waitcnt vmcnt(0)" ::: "memory");
        }
        __syncthreads();   // block released with clean L1
    }
}

extern "C" void kernel_launch(void* const* d_in, const int* in_sizes, int n_in,
                              void* d_out, int out_size, void* d_ws, size_t ws_size,
                              hipStream_t stream)
{
    const float* xp  = (const float*)d_in[0];
    const float* wih = (const float*)d_in[1];
    const float* whh = (const float*)d_in[2];
    const float* bih = (const float*)d_in[3];
    const float* bhh = (const float*)d_in[4];
    const float* wt  = (const float*)d_in[5];
    const float* wfc = (const float*)d_in[6];
    const float* bfc = (const float*)d_in[7];
    float* outp = (float*)d_out;
    float* ws   = (float*)d_ws;

    // zero flags + rank counters each call (graph-capturable)
    (void)hipMemsetAsync(d_ws, 0, 4096, stream);

    hipLaunchKernelGGL(lstm_fused, dim3(GRID), dim3(THREADS), 0, stream,
                       xp, wih, whh, bih, bhh, wt, wfc, bfc, outp, ws);
}